// Round 1
// baseline (371.622 us; speedup 1.0000x reference)
//
#include <hip/hip_runtime.h>

// FP32 bit-pulse -> FP8 E4M3 bit-pulse converter.
//
// v2: LDS-transpose version. The v1 kernel (one thread per value, 8x float4
// loads at 128 B lane stride) was VMEM-request-bound at ~0.9 TB/s effective.
// Here each block stages a 32 KB input tile with fully coalesced loads
// (16 B/lane, contiguous across the wave), reduces each float4 to a 4-bit
// nibble in LDS, transposes via LDS, and writes output through an LDS stage
// with fully contiguous float4 stores.
//
// LDS layout notes:
//  - nib[v*9 + k]: 8 nibble-words per value + 1 pad word. Read stride of
//    9 dwords is coprime with 32 banks -> conflict-free gather in pass 2.
//  - ostg: linear; write at 32 B lane stride spreads evenly over all 8
//    bank-groups (LDS time is negligible either way: ~17 KB/block total).

constexpr int VPB = 256;  // values per block == blockDim.x

__global__ __launch_bounds__(256) void fp8cvt_kernel(const float4* __restrict__ in,
                                                     float4* __restrict__ out,
                                                     int n) {
    __shared__ unsigned nib[VPB * 9];     // 9216 B
    __shared__ float4   ostg[VPB * 2];    // 8192 B

    const int t      = threadIdx.x;
    const int blockV = blockIdx.x * VPB;       // first value of this block
    const int rem    = n - blockV;             // values handled here (<= VPB)
    const float4* pin = in + (size_t)blockV * 8;

    // ---- pass 1: coalesced load of the 2048-float4 tile -> nibbles in LDS ----
    if (rem >= VPB) {
#pragma unroll
        for (int it = 0; it < 8; ++it) {
            int j = it * VPB + t;              // chunk index within tile
            float4 v = pin[j];
            unsigned b = ((unsigned)(v.x != 0.0f) << 3) |
                         ((unsigned)(v.y != 0.0f) << 2) |
                         ((unsigned)(v.z != 0.0f) << 1) |
                          (unsigned)(v.w != 0.0f);
            nib[(j >> 3) * 9 + (j & 7)] = b;
        }
    } else {
        int jmax = rem * 8;
        for (int it = 0; it < 8; ++it) {
            int j = it * VPB + t;
            if (j < jmax) {
                float4 v = pin[j];
                unsigned b = ((unsigned)(v.x != 0.0f) << 3) |
                             ((unsigned)(v.y != 0.0f) << 2) |
                             ((unsigned)(v.z != 0.0f) << 1) |
                              (unsigned)(v.w != 0.0f);
                nib[(j >> 3) * 9 + (j & 7)] = b;
            }
        }
    }
    __syncthreads();

    // ---- pass 2: assemble word, FP32->FP8 E4M3 RNE conversion, stage out ----
    if (t < rem) {
        unsigned word = 0u;
#pragma unroll
        for (int k = 0; k < 8; ++k) word = (word << 4) | nib[t * 9 + k];

        unsigned s    = word >> 31;
        int      exp  = (int)((word >> 23) & 0xFF);
        unsigned mant = word & 0x7FFFFFu;

        // normal path: exp8 = exp - 120, RNE 23 -> 3 mantissa bits
        unsigned kept  = mant >> 20;
        unsigned R     = (mant >> 19) & 1u;
        unsigned S     = (mant & ((1u << 19) - 1u)) != 0u;
        unsigned L     = kept & 1u;
        unsigned mr    = kept + (R & (S | L));
        unsigned carry = mr >> 3;
        unsigned mant_norm = carry ? 0u : (mr & 7u);
        int      exp_norm  = exp - 120 + (int)carry;

        // subnormal path (117 <= exp <= 120)
        unsigned full = (1u << 23) | mant;
        int sh = 141 - exp;
        sh = sh < 1 ? 1 : (sh > 24 ? 24 : sh);
        unsigned kept_s = full >> sh;
        unsigned Rs = (full >> (sh - 1)) & 1u;
        unsigned Ss = (full & ((1u << (sh - 1)) - 1u)) != 0u;
        unsigned Ls = kept_s & 1u;
        unsigned ms = kept_s + (Rs & (Ss | Ls));
        unsigned sub_of   = (ms >= 8u);
        unsigned sub_exp  = sub_of ? 1u : 0u;
        unsigned sub_mant = sub_of ? 0u : ms;

        // select overflow / subnormal / underflow / normal
        int exp8, mant8;
        if (exp > 134)                      { exp8 = 15;            mant8 = 6; }
        else if (exp >= 117 && exp <= 120)  { exp8 = (int)sub_exp;  mant8 = (int)sub_mant; }
        else if (exp < 117)                 { exp8 = 0;             mant8 = 0; }
        else                                { exp8 = exp_norm;      mant8 = (int)mant_norm; }

        float4 o0, o1;
        o0.x = (float)s;
        o0.y = (float)((exp8 >> 3) & 1);
        o0.z = (float)((exp8 >> 2) & 1);
        o0.w = (float)((exp8 >> 1) & 1);
        o1.x = (float)(exp8 & 1);
        o1.y = (float)((mant8 >> 2) & 1);
        o1.z = (float)((mant8 >> 1) & 1);
        o1.w = (float)(mant8 & 1);

        ostg[2 * t]     = o0;
        ostg[2 * t + 1] = o1;
    }
    __syncthreads();

    // ---- pass 3: fully coalesced float4 stores ----
    float4* pout = out + (size_t)blockV * 2;
    int m = (rem >= VPB) ? (2 * VPB) : (2 * rem);
    if (t < m)        pout[t]        = ostg[t];
    if (t + VPB < m)  pout[t + VPB]  = ostg[t + VPB];
}

extern "C" void kernel_launch(void* const* d_in, const int* in_sizes, int n_in,
                              void* d_out, int out_size, void* d_ws, size_t ws_size,
                              hipStream_t stream) {
    const float4* in  = (const float4*)d_in[0];
    float4*       out = (float4*)d_out;
    int n = in_sizes[0] / 32;   // number of FP32 values
    int block = VPB;
    int grid  = (n + VPB - 1) / VPB;
    fp8cvt_kernel<<<grid, block, 0, stream>>>(in, out, n);
}